// Round 3
// baseline (78302.179 us; speedup 1.0000x reference)
//
#include <hip/hip_runtime.h>
#include <cstdint>
#include <cmath>

#define FEAT 256
#define GATES 1024
#define BS 64
#define SEQ 2048
#define NEG_BIG -10000.0f
#define MIN_SEG 3.0f

#define NSLICE 8          // gate-row slices (32 features each)
#define NB 2              // batches per group
#define NGRP 32           // BS / NB
#define FPS 32            // features per slice
#define JCOLS 128         // 4 gates * FPS rows per slice
#define KTOT 512          // 256 h + 256 x

// ws layout (floats). Total sync region = 43008 floats = 168 KB.
#define FLAGS_FLOATS (NGRP * NSLICE * 32)          // uint flags, 128B apart
#define HX_OFF   FLAGS_FLOATS                      // [2][NGRP][NB][FEAT]
#define HX_FLOATS (2 * NGRP * NB * FEAT)
#define POL_OFF  (HX_OFF + HX_FLOATS)              // [2][NGRP][NSLICE][4]
#define POL_FLOATS (2 * NGRP * NSLICE * 4)
#define SYNC_FLOATS (POL_OFF + POL_FLOATS)

__global__ __launch_bounds__(256, 1) void seq_kernel(
    const float* __restrict__ x,
    const float* __restrict__ W_ih, const float* __restrict__ W_hh,
    const float* __restrict__ b_ih, const float* __restrict__ b_hh,
    const float* __restrict__ Wp, const float* __restrict__ bp,
    float* __restrict__ ws, float* __restrict__ out_b, float* __restrict__ out_sel)
{
    const int bid = blockIdx.x;
    const int s   = bid >> 5;        // slice 0..7
    const int p   = bid & 31;        // batch-group 0..31 (all 8 slice-blocks of a
                                     // group share bid%8 -> same XCD under round-robin)
    const int tid = threadIdx.x;
    const int kc  = tid & 15;        // k-chunk (lane bits 0..3 -> butterfly)
    const int jq  = tid >> 4;        // j-octet 0..15
    const int koff = kc * 32;        // this thread's 32-k window in [h(256); x(256)]

    unsigned int* flags = (unsigned int*)ws + (size_t)p * (NSLICE * 32);
    float* hx  = ws + HX_OFF;
    float* pol = ws + POL_OFF;

    __shared__ __align__(16) float kin[2][NB][KTOT];   // [buf][b][h(256); x(256)]
    __shared__ float G_lds[NB][JCOLS];
    __shared__ float polbuf[NSLICE * 4];
    __shared__ float s_prev[NB];

    // ---- weight slice -> 256 registers (stationary for all 2048 steps) ----
    float w[32][8];
#pragma unroll
    for (int jj = 0; jj < 8; ++jj) {
        int jcol = jq * 8 + jj;              // [g][f'] ordering
        int g = jcol >> 5, fp = jcol & 31;
        int j = g * FEAT + s * FPS + fp;     // global gate row
        const float* r = (kc < 8)
            ? (W_hh + (size_t)j * FEAT + koff)
            : (W_ih + (size_t)j * (FEAT + 1) + 1 + (koff - FEAT));
#pragma unroll
        for (int kk = 0; kk < 32; ++kk) w[kk][jj] = r[kk];
    }

    const int sb_b = tid >> 5, sb_f = tid & 31;   // LSTM-update role (tid < 64)
    float biasr[4] = {}, wpbr[4] = {};
    float wp0 = 0.f, wp1 = 0.f, c_reg = 0.f;
    if (tid < 64) {
#pragma unroll
        for (int g = 0; g < 4; ++g) {
            int j = g * FEAT + s * FPS + sb_f;
            biasr[g] = b_ih[j] + b_hh[j];
            wpbr[g]  = W_ih[(size_t)j * (FEAT + 1)];   // prev-boundary input column
        }
        wp0 = Wp[s * FPS + sb_f];
        wp1 = Wp[FEAT + s * FPS + sb_f];
    }
    float prevb = 0.f, flagst = 0.f;              // decision state (tid 0 / 32)
    const float bp0 = bp[0], bp1 = bp[1];
    const int bb0 = p * NB;

    if (tid == 0 || tid == 32) s_prev[tid >> 5] = 0.f;
    if (tid < 128) {                               // h(-1)=0, x(0) into kin[0]
        int b = tid >> 6, k4 = (tid & 63) * 4;
        *(float4*)&kin[0][b][k4] = make_float4(0.f, 0.f, 0.f, 0.f);
        *(float4*)&kin[0][b][FEAT + k4] =
            *(const float4*)&x[((size_t)(bb0 + b) * SEQ + 0) * FEAT + k4];
    }
    __syncthreads();

    for (int t = 0; t <= SEQ; ++t) {
        // phase 1: wait for all slices to have published step t-1
        if (t > 0 && tid < NSLICE) {
            int guard = 0;
            while (__hip_atomic_load(&flags[tid * 32], __ATOMIC_ACQUIRE,
                                     __HIP_MEMORY_SCOPE_AGENT) < (unsigned)t) {
                if (++guard > (1 << 22)) break;    // bug -> visible fail, not hang
            }
        }
        __syncthreads();                           // A
        __threadfence();                           // acquire: invalidate L1

        const int cur = t & 1;                     // buffer for this step's inputs
        const int rb  = (t + 1) & 1;               // global buf holding h(t-1)/pol(t-1)
        if (t > 0 && t < SEQ && tid < 128) {       // stage h(t-1) -> kin[cur] h-part
            int b = tid >> 6, k4 = (tid & 63) * 4;
            *(float4*)&kin[cur][b][k4] =
                *(const float4*)&hx[(((size_t)rb * NGRP + p) * NB + b) * FEAT + k4];
        }
        if (t > 0 && tid >= 128 && tid < 128 + NSLICE * 4)
            polbuf[tid - 128] = pol[((size_t)rb * NGRP + p) * (NSLICE * 4) + (tid - 128)];
        __syncthreads();                           // B

        // phase 2: decision for step t-1 (redundant, bit-identical in all blocks)
        if (t > 0 && (tid == 0 || tid == 32)) {
            int b = tid >> 5;
            float l0 = bp0, l1 = bp1;
#pragma unroll
            for (int ss = 0; ss < NSLICE; ++ss) {
                l0 += polbuf[ss * 4 + b * 2 + 0];
                l1 += polbuf[ss * 4 + b * 2 + 1];
            }
            if (flagst > 0.0f) l1 += NEG_BIG;
            int samp = (l1 > l0) ? 1 : 0;
            float a0 = l0 * 0.5f, a1 = l1 * 0.5f;  // logits / TAU, TAU = 2
            float m = fmaxf(a0, a1);
            float lse = m + logf(expf(a0 - m) + expf(a1 - m));
            if (s == 0) {
                out_b[(size_t)(bb0 + b) * SEQ + (t - 1)]   = (float)samp;
                out_sel[(size_t)(bb0 + b) * SEQ + (t - 1)] = (samp ? a1 : a0) - lse;
            }
            flagst = (flagst > 0.0f) ? (flagst - 1.0f) : flagst;
            if (samp) flagst = MIN_SEG;
            prevb = (float)samp;
            s_prev[b] = prevb;
        }
        if (t == SEQ) break;

        // phase 3: prefetch x(t+1) (independent of recurrence; lands before C)
        float4 xf;
        const bool pf = (t + 1 < SEQ) && (tid < 128);
        const int pb = tid >> 6, pk4 = (tid & 63) * 4;
        if (pf) xf = *(const float4*)&x[((size_t)(bb0 + pb) * SEQ + (t + 1)) * FEAT + pk4];

        // phase 4: K=512 matvec against register-resident weights
        float accf[NB][8] = {};
#pragma unroll
        for (int q = 0; q < 8; ++q) {
            float4 h0 = *(const float4*)&kin[cur][0][koff + q * 4];
            float4 h1 = *(const float4*)&kin[cur][1][koff + q * 4];
            float hv0[4] = {h0.x, h0.y, h0.z, h0.w};
            float hv1[4] = {h1.x, h1.y, h1.z, h1.w};
#pragma unroll
            for (int r = 0; r < 4; ++r)
#pragma unroll
                for (int jj = 0; jj < 8; ++jj) {
                    accf[0][jj] = fmaf(hv0[r], w[q * 4 + r][jj], accf[0][jj]);
                    accf[1][jj] = fmaf(hv1[r], w[q * 4 + r][jj], accf[1][jj]);
                }
        }
        // phase 5: butterfly reduce across kc (lane bits 0..3)
#pragma unroll
        for (int off = 1; off <= 8; off <<= 1)
#pragma unroll
            for (int b2 = 0; b2 < NB; ++b2)
#pragma unroll
                for (int jj = 0; jj < 8; ++jj)
                    accf[b2][jj] += __shfl_xor(accf[b2][jj], off, 64);
        if (kc == 0)
#pragma unroll
            for (int b2 = 0; b2 < NB; ++b2)
#pragma unroll
                for (int jj = 0; jj < 8; ++jj)
                    G_lds[b2][jq * 8 + jj] = accf[b2][jj];
        if (pf) *(float4*)&kin[rb][pb][FEAT + pk4] = xf;   // x(t+1) into other buf
        __syncthreads();                           // C

        // phase 6: LSTM update + policy partials (threads 0..63)
        if (tid < 64) {
            float pv = s_prev[sb_b];
            float gi = G_lds[sb_b][ 0 + sb_f] + biasr[0] + pv * wpbr[0];
            float gf = G_lds[sb_b][32 + sb_f] + biasr[1] + pv * wpbr[1];
            float gg = G_lds[sb_b][64 + sb_f] + biasr[2] + pv * wpbr[2];
            float go = G_lds[sb_b][96 + sb_f] + biasr[3] + pv * wpbr[3];
            float ig = 1.f / (1.f + expf(-gi));
            float fg = 1.f / (1.f + expf(-gf));
            float gt = tanhf(gg);
            float og = 1.f / (1.f + expf(-go));
            c_reg = fg * c_reg + ig * gt;
            float h = og * tanhf(c_reg);
            hx[(((size_t)cur * NGRP + p) * NB + sb_b) * FEAT + s * FPS + sb_f] = h;
            float p0 = h * wp0, p1 = h * wp1;
#pragma unroll
            for (int off2 = 16; off2 > 0; off2 >>= 1) {    // within 32-lane half
                p0 += __shfl_xor(p0, off2, 64);
                p1 += __shfl_xor(p1, off2, 64);
            }
            if (sb_f == 0) {
                float* pp = &pol[(((size_t)cur * NGRP + p) * NSLICE + s) * 4 + sb_b * 2];
                pp[0] = p0; pp[1] = p1;
            }
        }
        // phase 7: publish
        __threadfence();                           // release
        __syncthreads();                           // D
        if (tid == 0)
            __hip_atomic_store(&flags[s * 32], (unsigned)(t + 1),
                               __ATOMIC_RELEASE, __HIP_MEMORY_SCOPE_AGENT);
    }
}

extern "C" void kernel_launch(void* const* d_in, const int* in_sizes, int n_in,
                              void* d_out, int out_size, void* d_ws, size_t ws_size,
                              hipStream_t stream)
{
    const float* x    = (const float*)d_in[0];
    // d_in[1] = label (unused by the reference forward)
    const float* W_ih = (const float*)d_in[2];
    const float* W_hh = (const float*)d_in[3];
    const float* b_ih = (const float*)d_in[4];
    const float* b_hh = (const float*)d_in[5];
    const float* Wp   = (const float*)d_in[6];
    const float* bp   = (const float*)d_in[7];

    float* ws      = (float*)d_ws;
    float* out_b   = (float*)d_out;
    float* out_sel = out_b + (size_t)BS * SEQ;

    // zero sync region (flags/hx/pol) every call -> deterministic, capture-safe
    hipMemsetAsync(d_ws, 0, SYNC_FLOATS * sizeof(float), stream);

    hipLaunchKernelGGL(seq_kernel, dim3(NSLICE * NGRP), dim3(256), 0, stream,
                       x, W_ih, W_hh, b_ih, b_hh, Wp, bp, ws, out_b, out_sel);
}